// Round 1
// baseline (407.820 us; speedup 1.0000x reference)
//
#include <hip/hip_runtime.h>
#include <stdint.h>

typedef unsigned long long u64;
typedef unsigned int u32;

#define TOPK 100
#define NCLS 80
#define CAND_CAP 3072   // ~1850 local maxima expected; hard theoretical max 4096
#define TIE_CAP 128

__device__ __forceinline__ u32 order_f32(float f) {
  u32 b = __float_as_uint(f);
  return (b & 0x80000000u) ? ~b : (b | 0x80000000u);
}
__device__ __forceinline__ float unorder_f32(u32 u) {
  u32 b = (u & 0x80000000u) ? (u & 0x7FFFFFFFu) : ~u;
  return __uint_as_float(b);
}

// descending bitonic sort of 128 u64 keys in LDS; all 256 threads must call
__device__ __forceinline__ void bitonic128_desc(u64* a, int tid) {
  for (int k = 2; k <= 128; k <<= 1) {
    for (int j = k >> 1; j > 0; j >>= 1) {
      __syncthreads();
      if (tid < 128) {
        int ixj = tid ^ j;
        if (ixj > tid) {
          u64 x = a[tid], y = a[ixj];
          bool desc = ((tid & k) == 0);
          if ((x < y) == desc) { a[tid] = y; a[ixj] = x; }
        }
      }
    }
  }
  __syncthreads();
}

// Kernel 1: one block per (batch, class) plane.
// Streams 128x128 raw heatmap, 3x3 NMS via shuffles + rolling rows,
// compacts local maxima, exact top-100 via radix select (ties: lowest idx),
// sorts winners (value desc, idx asc), writes 100 keys per plane.
__global__ __launch_bounds__(256) void k1_nms_class_topk(
    const float* __restrict__ hm, u64* __restrict__ out_keys) {
  __shared__ u64 s_cand[CAND_CAP];
  __shared__ u64 s_win[128];
  __shared__ u64 s_tie[TIE_CAP];
  __shared__ int s_hist[256];
  __shared__ int s_cnt, s_gt, s_tc, s_krem;
  __shared__ u32 s_prefix;

  const int tid = threadIdx.x;
  const int lane = tid & 63;
  const int wid = tid >> 6;
  if (tid == 0) { s_cnt = 0; s_gt = 0; s_tc = 0; }
  __syncthreads();

  const int bc = blockIdx.x;
  const u32 cls = (u32)(bc % NCLS);
  const float* __restrict__ plane = hm + (size_t)bc * 16384;

  const float NEG = -__builtin_inff();
  // each wave owns rows [wid*32, wid*32+32); streams with 1-row halo
  const int r0 = wid * 32;
  float hA0 = NEG, hA1 = NEG, hB0 = NEG, hB1 = NEG, cB0 = NEG, cB1 = NEG;
  for (int ld = r0 - 1; ld <= r0 + 32; ++ld) {
    float c0, c1;
    if (ld >= 0 && ld < 128) {
      const float2 v = *(const float2*)(plane + (ld << 7) + (lane << 1));
      c0 = v.x; c1 = v.y;
    } else {
      c0 = NEG; c1 = NEG;
    }
    float left = __shfl_up(c1, 1);
    if (lane == 0) left = NEG;                 // SAME padding = -inf
    float right = __shfl_down(c0, 1);
    if (lane == 63) right = NEG;
    const float m01 = fmaxf(c0, c1);
    const float h0 = fmaxf(left, m01);         // hmax of (c-1,c,c+1) at col 2*lane
    const float h1 = fmaxf(m01, right);        // at col 2*lane+1
    if (ld >= r0 + 1) {
      // emit row ld-1: vertical max of hmax rows (ld-2, ld-1, ld)
      const float v0 = fmaxf(fmaxf(hA0, hB0), h0);
      const float v1 = fmaxf(fmaxf(hA1, hB1), h1);
      const int base_idx = ((ld - 1) << 7) + (lane << 1);
      if (cB0 == v0) {  // center >= all 8 neighbors (plateau-keeping, == ref)
        int p = atomicAdd(&s_cnt, 1);
        if (p < CAND_CAP)
          s_cand[p] = ((u64)order_f32(cB0) << 32) | (u32)((base_idx << 7) | cls);
      }
      if (cB1 == v1) {
        int p = atomicAdd(&s_cnt, 1);
        if (p < CAND_CAP)
          s_cand[p] = ((u64)order_f32(cB1) << 32) | (u32)(((base_idx + 1) << 7) | cls);
      }
    }
    hA0 = hB0; hA1 = hB1; hB0 = h0; hB1 = h1; cB0 = c0; cB1 = c1;
  }
  __syncthreads();

  const int n = min(s_cnt, CAND_CAP);
  const u64 PADKEY = ((u64)order_f32(-1e30f)) << 32;  // ranks below any real value

  if (tid < 128) s_win[tid] = (tid < TOPK) ? PADKEY : 0ull;
  __syncthreads();

  if (n > TOPK) {
    // 4-pass MSB radix select: exact value of the 100th largest
    if (tid == 0) { s_prefix = 0u; s_krem = TOPK; }
    __syncthreads();
    for (int p = 3; p >= 0; --p) {
      s_hist[tid] = 0;
      __syncthreads();
      const int shift = p << 3;
      const u32 himask = (p == 3) ? 0u : (0xFFFFFFFFu << (shift + 8));
      const u32 pref = s_prefix;
      for (int i = tid; i < n; i += 256) {
        const u32 u = (u32)(s_cand[i] >> 32);
        if ((u & himask) == pref) atomicAdd(&s_hist[(u >> shift) & 255], 1);
      }
      __syncthreads();
      if (tid == 0) {
        int K = s_krem, cum = 0, chosen = 0;
        for (int d = 255; d >= 0; --d) {
          const int c = s_hist[d];
          if (cum + c >= K) { chosen = d; break; }
          cum += c;
        }
        s_prefix = pref | ((u32)chosen << shift);
        s_krem = K - cum;
      }
      __syncthreads();
    }
    const u32 T = s_prefix;
    for (int i = tid; i < n; i += 256) {
      const u64 k = s_cand[i];
      const u32 u = (u32)(k >> 32);
      if (u > T) {
        const int p = atomicAdd(&s_gt, 1);  // guaranteed <= 99
        s_win[p] = k;
      } else if (u == T) {
        const int p = atomicAdd(&s_tc, 1);
        if (p < TIE_CAP) s_tie[p] = k;
      }
    }
    __syncthreads();
    if (tid == 0) {
      // fill remaining slots from value-ties, lowest spatial idx first (== top_k)
      const int gt = s_gt;
      const int need = TOPK - gt;
      const int tc = min(s_tc, TIE_CAP);
      for (int k2 = 0; k2 < need; ++k2) {
        int best = -1;
        u32 bi = 0xFFFFFFFFu;
        for (int j = 0; j < tc; ++j) {
          const u64 kk = s_tie[j];
          if (kk == 0xFFFFFFFFFFFFFFFFull) continue;
          const u32 sidx = ((u32)kk) >> 7;
          if (sidx < bi) { bi = sidx; best = j; }
        }
        if (best < 0) break;
        s_win[gt + k2] = s_tie[best];
        s_tie[best] = 0xFFFFFFFFFFFFFFFFull;
      }
    }
    __syncthreads();
  } else {
    for (int i = tid; i < n; i += 256) s_win[i] = s_cand[i];
    __syncthreads();
  }

  // sort: value desc, idx asc  (invert low 32 bits so plain u64-desc works)
  if (tid < 128) {
    u64 k = s_win[tid];
    if (tid < TOPK) k = (k & 0xFFFFFFFF00000000ull) | (u64)(u32)(~(u32)k);
    s_win[tid] = k;
  }
  __syncthreads();
  bitonic128_desc(s_win, tid);
  if (tid < TOPK) {
    const u64 k = s_win[tid];
    out_keys[(size_t)bc * TOPK + tid] =
        (k & 0xFFFFFFFF00000000ull) | (u64)(u32)(~(u32)k);
  }
}

// Kernel 2: one block per batch. Top-100 of the 8000 per-class keys with
// reference tie-break (lowest flat position), sort desc, decode & write.
__global__ __launch_bounds__(256) void k2_batch_topk_decode(
    const u64* __restrict__ keys, const float* __restrict__ off,
    const float* __restrict__ wh, float* __restrict__ out) {
  __shared__ u32 s_u[NCLS * TOPK];   // 32 KB: value part only
  __shared__ u64 s_win[128];
  __shared__ u64 s_tie[TIE_CAP];
  __shared__ int s_hist[256];
  __shared__ int s_gt, s_tc, s_krem;
  __shared__ u32 s_prefix;

  const int tid = threadIdx.x;
  const int b = blockIdx.x;
  const int n = NCLS * TOPK;  // 8000
  const u64* __restrict__ src = keys + (size_t)b * n;

  for (int i = tid; i < n; i += 256) s_u[i] = (u32)(src[i] >> 32);
  if (tid == 0) { s_prefix = 0u; s_krem = TOPK; s_gt = 0; s_tc = 0; }
  __syncthreads();

  for (int p = 3; p >= 0; --p) {
    s_hist[tid] = 0;
    __syncthreads();
    const int shift = p << 3;
    const u32 himask = (p == 3) ? 0u : (0xFFFFFFFFu << (shift + 8));
    const u32 pref = s_prefix;
    for (int i = tid; i < n; i += 256) {
      const u32 u = s_u[i];
      if ((u & himask) == pref) atomicAdd(&s_hist[(u >> shift) & 255], 1);
    }
    __syncthreads();
    if (tid == 0) {
      int K = s_krem, cum = 0, chosen = 0;
      for (int d = 255; d >= 0; --d) {
        const int c = s_hist[d];
        if (cum + c >= K) { chosen = d; break; }
        cum += c;
      }
      s_prefix = pref | ((u32)chosen << shift);
      s_krem = K - cum;
    }
    __syncthreads();
  }
  const u32 T = s_prefix;
  if (tid < 128) s_win[tid] = 0ull;
  __syncthreads();
  // entry = value<<32 | (7999 - flat_pos): plain u64 order == reference order
  for (int i = tid; i < n; i += 256) {
    const u32 u = s_u[i];
    if (u >= T) {
      const u64 e = ((u64)u << 32) | (u64)(u32)(7999 - i);
      if (u > T) {
        const int p = atomicAdd(&s_gt, 1);
        s_win[p] = e;
      } else {
        const int p = atomicAdd(&s_tc, 1);
        if (p < TIE_CAP) s_tie[p] = e;
      }
    }
  }
  __syncthreads();
  if (tid == 0) {
    const int gt = s_gt;
    const int need = TOPK - gt;
    const int tc = min(s_tc, TIE_CAP);
    for (int k2 = 0; k2 < need; ++k2) {
      int best = -1;
      u32 bl = 0;
      for (int j = 0; j < tc; ++j) {
        const u64 kk = s_tie[j];
        if (kk == 0xFFFFFFFFFFFFFFFFull) continue;
        const u32 low = (u32)kk;
        if (best < 0 || low > bl) { bl = low; best = j; }  // largest = lowest flat pos
      }
      if (best < 0) break;
      s_win[gt + k2] = s_tie[best];
      s_tie[best] = 0xFFFFFFFFFFFFFFFFull;
    }
  }
  __syncthreads();
  bitonic128_desc(s_win, tid);

  if (tid < TOPK) {
    const u64 k = s_win[tid];
    const u32 u = (u32)(k >> 32);
    const int i = 7999 - (int)((u32)k & 0xFFFFu);
    const u64 orig = src[i];
    const u32 low = (u32)orig;
    const int idx = (int)((low >> 7) & 16383);
    const int cls = (int)(low & 127);
    const float val = unorder_f32(u);
    const float score = 1.0f / (1.0f + expf(-val));   // sigmoid of raw value
    const bool keep = score > 0.05f;
    const float x = (float)(idx & 127);
    const float y = (float)(idx >> 7);
    const size_t ob = (size_t)b * 32768;
    const float ox = off[ob + idx];
    const float oy = off[ob + 16384 + idx];
    const float bw = wh[ob + idx];
    const float bh = wh[ob + 16384 + idx];
    const float xs = x + ox;
    const float ys = y + oy;
    out[b * TOPK + tid] = keep ? score : -1.0f;
    out[3200 + b * TOPK + tid] = keep ? (float)cls : -1.0f;
    float* bb = out + 6400 + ((size_t)(b * TOPK + tid)) * 4;
    if (keep) {
      bb[0] = (xs - bw * 0.5f) * 4.0f;
      bb[1] = (ys - bh * 0.5f) * 4.0f;
      bb[2] = (xs + bw * 0.5f) * 4.0f;
      bb[3] = (ys + bh * 0.5f) * 4.0f;
    } else {
      bb[0] = 0.0f; bb[1] = 0.0f; bb[2] = 0.0f; bb[3] = 0.0f;
    }
  }
}

extern "C" void kernel_launch(void* const* d_in, const int* in_sizes, int n_in,
                              void* d_out, int out_size, void* d_ws, size_t ws_size,
                              hipStream_t stream) {
  const float* hm  = (const float*)d_in[0];   // (32,80,128,128) f32
  const float* off = (const float*)d_in[1];   // (32,2,128,128)  f32
  const float* wh  = (const float*)d_in[2];   // (32,2,128,128)  f32
  float* out = (float*)d_out;                 // 3200 + 3200 + 12800 f32
  u64* keys = (u64*)d_ws;                     // needs 32*80*100*8 = 2.05 MB

  k1_nms_class_topk<<<32 * NCLS, 256, 0, stream>>>(hm, keys);
  k2_batch_topk_decode<<<32, 256, 0, stream>>>(keys, off, wh, out);
}